// Round 15
// baseline (349.808 us; speedup 1.0000x reference)
//
#include <hip/hip_runtime.h>
#include <stdint.h>

// ---- problem constants (fixed by reference) ----
constexpr int DMODEL = 1024;
constexpr int NH     = 16;
constexpr int DHD    = 64;
constexpr int BS     = 8;
constexpr int QLEN   = 32;
constexpr int KLEN   = 4000;
constexpr int NCTX   = 20;
constexpr int PLEN   = 200;

typedef __bf16 bf16_t;
typedef bf16_t bf16x8 __attribute__((ext_vector_type(8)));
typedef float  f32x4  __attribute__((ext_vector_type(4)));

__device__ __forceinline__ uint16_t f2bf(float f) {
  uint32_t u = __float_as_uint(f);
  u += 0x7FFF + ((u >> 16) & 1);   // round-to-nearest-even
  return (uint16_t)(u >> 16);
}

#define GLOAD_LDS16(gsrc, ldst) \
  __builtin_amdgcn_global_load_lds((const __attribute__((address_space(1))) void*)(gsrc), \
                                   (__attribute__((address_space(3))) void*)(ldst), 16, 0, 0)

// ---------------- mask dtype detector ----------------
__global__ void detect_mask(const uint32_t* __restrict__ m, int* __restrict__ flag) {
  if (threadIdx.x == 0 && blockIdx.x == 0)
    *flag = (m[0] == 0x01010101u) ? 1 : 0;   // 1 = byte-bool, 0 = int32
}

// ---------------- cast kv + input f32 -> bf16 ----------------
__global__ void cast_inputs(const float* __restrict__ kv, const float* __restrict__ inp,
                            uint16_t* __restrict__ kv16, uint16_t* __restrict__ in16) {
  const int NKV4 = (BS * KLEN * DMODEL) / 4;
  const int NIN4 = (BS * QLEN * DMODEL) / 4;
  const int total = NKV4 + NIN4;
  for (int i = blockIdx.x * blockDim.x + threadIdx.x; i < total; i += gridDim.x * blockDim.x) {
    float4 v; uint16_t* dst; int di;
    if (i < NKV4) { v = ((const float4*)kv)[i]; dst = kv16; di = i; }
    else          { v = ((const float4*)inp)[i - NKV4]; dst = in16; di = i - NKV4; }
    ushort4 o; o.x = f2bf(v.x); o.y = f2bf(v.y); o.z = f2bf(v.z); o.w = f2bf(v.w);
    ((ushort4*)dst)[di] = o;
  }
}

// ---------------- weight transpose-cast: W[1024][1024] f32 -> WT[N][K] bf16 ----------------
__global__ void wtrans(const float* __restrict__ w0, const float* __restrict__ w1,
                       const float* __restrict__ w2, const float* __restrict__ w3,
                       uint16_t* __restrict__ out) {
  __shared__ uint16_t sm[64][65];
  const float* W = (blockIdx.z == 0) ? w0 : (blockIdx.z == 1) ? w1 : (blockIdx.z == 2) ? w2 : w3;
  uint16_t* o = out + (size_t)blockIdx.z * DMODEL * DMODEL;
  int k0 = blockIdx.y * 64, n0 = blockIdx.x * 64;
  int t = threadIdx.x;
  for (int i = 0; i < 16; ++i) {
    int s = t + i * 256; int r = s >> 6, c = s & 63;
    sm[r][c] = f2bf(W[(size_t)(k0 + r) * DMODEL + n0 + c]);
  }
  __syncthreads();
  for (int i = 0; i < 16; ++i) {
    int s = t + i * 256; int r = s >> 6, c = s & 63;
    o[(size_t)(n0 + r) * DMODEL + k0 + c] = sm[c][r];   // WT[n][k] = W[k][n]
  }
}

// ---------------- small bf16 GEMM (Q proj / out proj) ----------------
template <int OUT_F32>
__global__ void __launch_bounds__(256) gemm_bt(const uint16_t* __restrict__ A,
                                               const uint16_t* __restrict__ Bt,
                                               void* __restrict__ Cv,
                                               int M, int N, int K) {
  __shared__ __align__(16) uint16_t As[128 * 32];
  __shared__ __align__(16) uint16_t Bs[128 * 32];
  const int m0 = blockIdx.x * 128, n0 = blockIdx.y * 128;
  const int tid = threadIdx.x, lane = tid & 63, wave = tid >> 6;
  const int wm = wave >> 1, wn = wave & 1;
  const int l15 = lane & 15, g = lane >> 4;
  const int sr = lane >> 2, sc = (lane & 3) * 8;
  const int c0 = wave * 2, c1 = wave * 2 + 1;
  f32x4 acc[4][4] = {};
  const int KT = K / 32;
  for (int kt = 0; kt < KT; ++kt) {
    __syncthreads();
    GLOAD_LDS16(A  + (size_t)(m0 + c0 * 16 + sr) * K + kt * 32 + sc, As + c0 * 512);
    GLOAD_LDS16(A  + (size_t)(m0 + c1 * 16 + sr) * K + kt * 32 + sc, As + c1 * 512);
    GLOAD_LDS16(Bt + (size_t)(n0 + c0 * 16 + sr) * K + kt * 32 + sc, Bs + c0 * 512);
    GLOAD_LDS16(Bt + (size_t)(n0 + c1 * 16 + sr) * K + kt * 32 + sc, Bs + c1 * 512);
    __syncthreads();
    bf16x8 a[4], b[4];
#pragma unroll
    for (int i = 0; i < 4; ++i)
      a[i] = *(const bf16x8*)&As[(wm * 64 + i * 16 + l15) * 32 + g * 8];
#pragma unroll
    for (int j = 0; j < 4; ++j)
      b[j] = *(const bf16x8*)&Bs[(wn * 64 + j * 16 + l15) * 32 + g * 8];
#pragma unroll
    for (int i = 0; i < 4; ++i)
#pragma unroll
      for (int j = 0; j < 4; ++j)
        acc[i][j] = __builtin_amdgcn_mfma_f32_16x16x32_bf16(a[i], b[j], acc[i][j], 0, 0, 0);
  }
#pragma unroll
  for (int i = 0; i < 4; ++i)
#pragma unroll
    for (int j = 0; j < 4; ++j) {
      int row = m0 + wm * 64 + i * 16 + g * 4;
      int col = n0 + wn * 64 + j * 16 + l15;
      if (OUT_F32) {
        float* C = (float*)Cv;
#pragma unroll
        for (int r = 0; r < 4; ++r) C[(size_t)(row + r) * N + col] = acc[i][j][r];
      } else {
        uint16_t* C = (uint16_t*)Cv;
#pragma unroll
        for (int r = 0; r < 4; ++r) C[(size_t)(row + r) * N + col] = f2bf(acc[i][j][r]);
      }
    }
}

// ---------------- merged K+V projection GEMM (exact round-9 text: measured 162 us) ----
__global__ void __launch_bounds__(512) gemm_kv(const uint16_t* __restrict__ A,
                                               const uint16_t* __restrict__ Bt,
                                               uint16_t* __restrict__ kmat,
                                               uint16_t* __restrict__ vt) {
  __shared__ __align__(16) uint16_t smem[65536];   // 128 KB
  const int orig = blockIdx.x;                      // 1000 = 8 * 125
  const int swz  = (orig & 7) * 125 + (orig >> 3);  // XCD-chunked bijection
  const int mb = swz >> 3, nb = swz & 7;            // n-fastest
  const int m0 = mb * 256, n0 = nb * 256;
  const int tid = threadIdx.x, lane = tid & 63, wid = tid >> 6;
  const int wm = wid >> 2, wn = wid & 3;            // 2x4 wave grid; wave tile 128x64
  const int l15 = lane & 15, g = lane >> 4;
  const int l3 = lane >> 3, l7 = lane & 7;
  const int cg = (l7 ^ (l3 & 7)) * 8;               // pre-swizzled source granule

  f32x4 acc[8][4] = {};

#define ABASE(bf) (smem + (bf) * 32768)
#define BBASE(bf) (smem + (bf) * 32768 + 16384)

  auto STAGE = [&](int bf, int kt) {
    const int colg = kt * 64 + cg;
#pragma unroll
    for (int ia = 0; ia < 4; ++ia) {                // 4 A-loads/wave: 8 rows each
      const int r0 = wid * 32 + ia * 8;
      GLOAD_LDS16(A + (size_t)(m0 + r0 + l3) * 1024 + colg, ABASE(bf) + r0 * 64);
    }
#pragma unroll
    for (int ib = 0; ib < 4; ++ib) {                // 4 B-loads/wave
      const int r0 = wid * 32 + ib * 8;
      GLOAD_LDS16(Bt + (size_t)(n0 + r0 + l3) * 1024 + colg, BBASE(bf) + r0 * 64);
    }
  };

  STAGE(0, 0);
  for (int kt = 0; kt < 16; ++kt) {
    const int bf = kt & 1;
    if (kt < 15) {
      STAGE(bf ^ 1, kt + 1);                         // 8 new loads in flight
      asm volatile("s_waitcnt vmcnt(8)" ::: "memory");  // tile kt landed; kt+1 stays in flight
    } else {
      asm volatile("s_waitcnt vmcnt(0)" ::: "memory");
    }
    asm volatile("s_barrier" ::: "memory");
#pragma unroll
    for (int kk = 0; kk < 2; ++kk) {
      bf16x8 af[8], bb[4];
#pragma unroll
      for (int mi = 0; mi < 8; ++mi) {
        const int row = wm * 128 + mi * 16 + l15;
        const int gr = (kk * 4 + g) ^ (row & 7);    // swizzled read -> conflict-free
        af[mi] = *(const bf16x8*)&ABASE(bf)[row * 64 + gr * 8];
      }
#pragma unroll
      for (int ni = 0; ni < 4; ++ni) {
        const int row = wn * 64 + ni * 16 + l15;
        const int gr = (kk * 4 + g) ^ (row & 7);
        bb[ni] = *(const bf16x8*)&BBASE(bf)[row * 64 + gr * 8];
      }
#pragma unroll
      for (int mi = 0; mi < 8; ++mi)
#pragma unroll
        for (int ni = 0; ni < 4; ++ni)
          acc[mi][ni] = __builtin_amdgcn_mfma_f32_16x16x32_bf16(af[mi], bb[ni], acc[mi][ni], 0, 0, 0);
    }
    asm volatile("s_barrier" ::: "memory");          // buf[bf] free for re-stage next iter
  }
#undef ABASE
#undef BBASE

  if (n0 < 1024) {
    // ---- K half: row-major store to kmat [32000][1024]
#pragma unroll
    for (int mi = 0; mi < 8; ++mi)
#pragma unroll
      for (int ni = 0; ni < 4; ++ni) {
        const int row = m0 + wm * 128 + mi * 16 + g * 4;
        const int col = n0 + wn * 64 + ni * 16 + l15;
#pragma unroll
        for (int r = 0; r < 4; ++r)
          kmat[(size_t)(row + r) * 1024 + col] = f2bf(acc[mi][ni][r]);
      }
  } else {
    // ---- V half: 256x256 LDS transpose (reuse all 128 KB) then coalesced vt store
#pragma unroll
    for (int mi = 0; mi < 8; ++mi)
#pragma unroll
      for (int ni = 0; ni < 4; ++ni) {
        const int dd = wn * 64 + ni * 16 + l15;        // head-dim within tile
        const int kk_tok = wm * 128 + mi * 16 + g * 4; // token within tile
#pragma unroll
        for (int r = 0; r < 4; ++r)
          smem[dd * 256 + kk_tok + r] = f2bf(acc[mi][ni][r]);
      }
    __syncthreads();
    const int hbase = (n0 - 1024) >> 6;               // 4 heads per 256-col tile
#pragma unroll
    for (int it = 0; it < 16; ++it) {
      const int sp = it * 512 + tid;                  // 8192 spans of 8 elems
      const int dd = sp >> 5, kk0 = (sp & 31) * 8;
      const int grow = m0 + kk0;                      // 8-span never straddles b (4000%8==0)
      const int b = grow / 4000, krel = grow - b * 4000;
      const int h = hbase + (dd >> 6), d = dd & 63;
      ulonglong2 v = *(const ulonglong2*)&smem[dd * 256 + kk0];
      *(ulonglong2*)&vt[(((size_t)(b * NH + h) * DHD + d) * KLEN) + krel] = v;
    }
  }
}

// ---------------- fused flash attention + collected, T14 K/V register prefetch ----
// Wave w owns context ctx = kc*4+w. NEW vs round 9: kb/vb double-buffered in regs;
// tile t+1's 8 global loads issue at the top of tile t's compute (fully unrolled loop
// so [t&1] indices are compile-time) — HBM latency hides under QK/softmax/PV.
__global__ void __launch_bounds__(256) fused_attn(const uint16_t* __restrict__ Q,
                                                  const uint16_t* __restrict__ Km,
                                                  const uint16_t* __restrict__ Vt,
                                                  const float* __restrict__ mask_add,
                                                  const void* __restrict__ maskb,
                                                  const int* __restrict__ flag,
                                                  const float* __restrict__ bias,
                                                  float* __restrict__ part,
                                                  float* __restrict__ coll) {
  __shared__ __align__(16) uint16_t plds[4][32 * 32];   // per-wave P tile (no barriers)
  const int kc = blockIdx.x, h = blockIdx.y, b = blockIdx.z;
  const int lane = threadIdx.x & 63, wave = threadIdx.x >> 6;
  const int l15 = lane & 15, g = lane >> 4;
  const int ctx = kc * 4 + wave;
  const int kbase = ctx * PLEN;
  const int fm = *flag;

  bf16x8 aq[2][2];
#pragma unroll
  for (int i = 0; i < 2; ++i)
#pragma unroll
    for (int ks = 0; ks < 2; ++ks)
      aq[i][ks] = *(const bf16x8*)&Q[(size_t)(b * QLEN + i * 16 + l15) * DMODEL + h * DHD + ks * 32 + g * 8];

  f32x4 o[2][4] = {};
  float mr[2][4], lr[2][4], cs[2][4];
#pragma unroll
  for (int i = 0; i < 2; ++i)
#pragma unroll
    for (int r = 0; r < 4; ++r) { mr[i][r] = -3e38f; lr[i][r] = 0.f; cs[i][r] = 0.f; }
  float cnt = 0.f;

  bf16x8 kb[2][2][2];   // [buf][j][ks]
  bf16x8 vb[2][4];      // [buf][j2]
  auto LOADKV = [&](int t, int pb) {
    const int k0 = kbase + t * 32;
#pragma unroll
    for (int j = 0; j < 2; ++j) {
      int kr = k0 + j * 16 + l15; if (kr > KLEN - 1) kr = KLEN - 1;
#pragma unroll
      for (int ks = 0; ks < 2; ++ks)
        kb[pb][j][ks] = *(const bf16x8*)&Km[(size_t)(b * KLEN + kr) * DMODEL + h * DHD + ks * 32 + g * 8];
    }
    int vc = k0 + g * 8; if (vc > KLEN - 8) vc = KLEN - 8;  // clamped; p=0 kills padded cols
#pragma unroll
    for (int j2 = 0; j2 < 4; ++j2)
      vb[pb][j2] = *(const bf16x8*)&Vt[((size_t)((b * NH + h) * DHD + j2 * 16 + l15)) * KLEN + vc];
  };

  LOADKV(0, 0);
#pragma unroll
  for (int t = 0; t < 7; ++t) {
    const int cur = t & 1;
    if (t < 6) LOADKV(t + 1, cur ^ 1);   // prefetch next tile; hides under this tile's compute
    const int k0 = kbase + t * 32;

    f32x4 sa[2][2] = {};
#pragma unroll
    for (int ks = 0; ks < 2; ++ks)
#pragma unroll
      for (int i = 0; i < 2; ++i)
#pragma unroll
        for (int j = 0; j < 2; ++j)
          sa[i][j] = __builtin_amdgcn_mfma_f32_16x16x32_bf16(aq[i][ks], kb[cur][j][ks], sa[i][j], 0, 0, 0);

    int colc[2]; bool vd[2], vm[2]; float ma[2];
#pragma unroll
    for (int j = 0; j < 2; ++j) {
      int col = k0 + j * 16 + l15;
      vd[j] = (col < kbase + PLEN);            // padding predicate (softmax)
      int cc = col; if (cc > KLEN - 1) cc = KLEN - 1;
      colc[j] = cc;
      ma[j] = mask_add[b * KLEN + cc];
      bool mk = fm ? (((const uint8_t*)maskb)[b * KLEN + cc] != 0)
                   : (((const int*)maskb)[b * KLEN + cc] != 0);
      vm[j] = vd[j] && mk;                     // collected predicate
    }

    float sv[2][2][4];
    float tmax[2][4];
#pragma unroll
    for (int i = 0; i < 2; ++i)
#pragma unroll
      for (int r = 0; r < 4; ++r) {
        tmax[i][r] = -3e38f;
        const int q = i * 16 + g * 4 + r;
        const size_t brow = (size_t)(h * QLEN + q) * KLEN;
#pragma unroll
        for (int j = 0; j < 2; ++j) {
          float raw = sa[i][j][r] + ma[j] + bias[brow + colc[j]];
          cs[i][r] += vm[j] ? raw : 0.f;
          float x = vd[j] ? raw : -3e38f;
          sv[i][j][r] = x;
          tmax[i][r] = fmaxf(tmax[i][r], x);
        }
      }
#pragma unroll
    for (int j = 0; j < 2; ++j) cnt += vm[j] ? 1.f : 0.f;

    // row-max over the 16-lane (l15) group
#pragma unroll
    for (int i = 0; i < 2; ++i)
#pragma unroll
      for (int r = 0; r < 4; ++r) {
        float v = tmax[i][r];
        v = fmaxf(v, __shfl_xor(v, 1)); v = fmaxf(v, __shfl_xor(v, 2));
        v = fmaxf(v, __shfl_xor(v, 4)); v = fmaxf(v, __shfl_xor(v, 8));
        tmax[i][r] = v;
      }
    float scale[2][4];
#pragma unroll
    for (int i = 0; i < 2; ++i)
#pragma unroll
      for (int r = 0; r < 4; ++r) {
        float mn = fmaxf(mr[i][r], tmax[i][r]);
        scale[i][r] = __expf(mr[i][r] - mn);
        mr[i][r] = mn;
        lr[i][r] *= scale[i][r];
      }
#pragma unroll
    for (int i = 0; i < 2; ++i)
#pragma unroll
      for (int j2 = 0; j2 < 4; ++j2)
#pragma unroll
        for (int r = 0; r < 4; ++r)
          o[i][j2][r] *= scale[i][r];
    // P = exp(s - m) -> bf16 -> per-wave LDS tile (rows=q, cols=k-in-tile)
#pragma unroll
    for (int i = 0; i < 2; ++i)
#pragma unroll
      for (int r = 0; r < 4; ++r) {
        const int q = i * 16 + g * 4 + r;
#pragma unroll
        for (int j = 0; j < 2; ++j) {
          float p = __expf(sv[i][j][r] - mr[i][r]);
          lr[i][r] += p;
          plds[wave][q * 32 + j * 16 + l15] = f2bf(p);
        }
      }
    bf16x8 ap[2];
#pragma unroll
    for (int i = 0; i < 2; ++i)
      ap[i] = *(const bf16x8*)&plds[wave][(i * 16 + l15) * 32 + g * 8];
#pragma unroll
    for (int i = 0; i < 2; ++i)
#pragma unroll
      for (int j2 = 0; j2 < 4; ++j2)
        o[i][j2] = __builtin_amdgcn_mfma_f32_16x16x32_bf16(ap[i], vb[cur][j2], o[i][j2], 0, 0, 0);
  }

  // reduce l / csum / cnt over the l15 group
#pragma unroll
  for (int i = 0; i < 2; ++i)
#pragma unroll
    for (int r = 0; r < 4; ++r) {
      float v = lr[i][r];
      v += __shfl_xor(v, 1); v += __shfl_xor(v, 2); v += __shfl_xor(v, 4); v += __shfl_xor(v, 8);
      lr[i][r] = v;
      float c = cs[i][r];
      c += __shfl_xor(c, 1); c += __shfl_xor(c, 2); c += __shfl_xor(c, 4); c += __shfl_xor(c, 8);
      cs[i][r] = c;
    }
  { float c = cnt; c += __shfl_xor(c, 1); c += __shfl_xor(c, 2); c += __shfl_xor(c, 4); c += __shfl_xor(c, 8); cnt = c; }

  float* pr = part + ((size_t)((b * NH + h) * NCTX + ctx)) * 32 * 72;
#pragma unroll
  for (int i = 0; i < 2; ++i)
#pragma unroll
    for (int j2 = 0; j2 < 4; ++j2)
#pragma unroll
      for (int r = 0; r < 4; ++r)
        pr[(i * 16 + g * 4 + r) * 72 + 8 + j2 * 16 + l15] = o[i][j2][r];
  if (l15 == 0) {
#pragma unroll
    for (int i = 0; i < 2; ++i)
#pragma unroll
      for (int r = 0; r < 4; ++r) {
        int q = i * 16 + g * 4 + r;
        pr[q * 72 + 0] = mr[i][r];
        pr[q * 72 + 1] = lr[i][r];
        coll[(((size_t)(b * NH + h)) * QLEN + q) * NCTX + ctx] = cs[i][r] / cnt;
      }
  }
}

// ---------------- combine 20 chunk partials -> ao16 ----------------
__global__ void __launch_bounds__(256) combine_attn(const float* __restrict__ part,
                                                    uint16_t* __restrict__ ao16) {
  const int t = threadIdx.x;
  const int row = blockIdx.x * 16 + (t >> 4);   // (b*16+h)*32+q
  const int ln = t & 15;
  const int bh = row >> 5, q = row & 31;
  const float* p0 = part + ((size_t)bh * 640 + q) * 72;   // 640 = 20*32
  float M = -3e38f;
#pragma unroll
  for (int c = 0; c < NCTX; ++c) M = fmaxf(M, p0[(size_t)c * 2304]);  // 2304 = 32*72
  float Z = 0.f, o0 = 0.f, o1 = 0.f, o2 = 0.f, o3 = 0.f;
  const int d0 = ln * 4;
  for (int c = 0; c < NCTX; ++c) {
    const float* pc = p0 + (size_t)c * 2304;
    float e = __expf(pc[0] - M);
    Z += e * pc[1];
    float4 ov = *(const float4*)&pc[8 + d0];
    o0 += e * ov.x; o1 += e * ov.y; o2 += e * ov.z; o3 += e * ov.w;
  }
  float iz = 1.f / Z;
  const int b = bh >> 4, h = bh & 15;
  ushort4 w; w.x = f2bf(o0 * iz); w.y = f2bf(o1 * iz); w.z = f2bf(o2 * iz); w.w = f2bf(o3 * iz);
  *(ushort4*)&ao16[(size_t)(b * QLEN + q) * DMODEL + h * DHD + d0] = w;
}

extern "C" void kernel_launch(void* const* d_in, const int* in_sizes, int n_in,
                              void* d_out, int out_size, void* d_ws, size_t ws_size,
                              hipStream_t stream) {
  const float* input     = (const float*)d_in[0];
  const float* kv        = (const float*)d_in[1];
  const float* mask_add  = (const float*)d_in[2];
  const void*  mask_bool = d_in[3];
  const float* bias      = (const float*)d_in[4];
  const float* Wq        = (const float*)d_in[5];
  const float* Wk        = (const float*)d_in[6];
  const float* Wv        = (const float*)d_in[7];
  const float* Wo        = (const float*)d_in[8];
  float* out  = (float*)d_out;
  float* coll = out + (size_t)BS * QLEN * DMODEL;

  char* ws = (char*)d_ws;
  size_t off = 0;
  auto alloc = [&](size_t bytes) { char* p = ws + off; off += (bytes + 255) & ~(size_t)255; return p; };
  uint16_t* kv16 = (uint16_t*)alloc((size_t)BS * KLEN * DMODEL * 2);
  uint16_t* in16 = (uint16_t*)alloc((size_t)BS * QLEN * DMODEL * 2);
  uint16_t* wt   = (uint16_t*)alloc((size_t)4 * DMODEL * DMODEL * 2);
  uint16_t* q16  = (uint16_t*)alloc((size_t)BS * QLEN * DMODEL * 2);
  uint16_t* kmat = (uint16_t*)alloc((size_t)BS * KLEN * DMODEL * 2);
  uint16_t* vt   = (uint16_t*)alloc((size_t)BS * KLEN * DMODEL * 2);
  float*    part = (float*)   alloc((size_t)BS * NH * NCTX * 32 * 72 * 4);
  uint16_t* ao16 = (uint16_t*)alloc((size_t)BS * QLEN * DMODEL * 2);
  int*      flag = (int*)alloc(256);

  uint16_t* WqT  = wt;
  uint16_t* WkvT = wt + (size_t)DMODEL * DMODEL;      // [WkT; WvT] contiguous, 2048 rows
  uint16_t* WoT  = wt + (size_t)3 * DMODEL * DMODEL;

  detect_mask<<<1, 64, 0, stream>>>((const uint32_t*)mask_bool, flag);
  cast_inputs<<<2048, 256, 0, stream>>>(kv, input, kv16, in16);
  wtrans<<<dim3(16, 16, 4), 256, 0, stream>>>(Wq, Wk, Wv, Wo, wt);
  gemm_bt<0><<<dim3(2, 8), 256, 0, stream>>>(in16, WqT, q16, BS * QLEN, DMODEL, DMODEL);
  gemm_kv<<<1000, 512, 0, stream>>>(kv16, WkvT, kmat, vt);
  fused_attn<<<dim3(5, NH, BS), 256, 0, stream>>>(q16, kmat, vt, mask_add, mask_bool, flag,
                                                  bias, part, coll);
  combine_attn<<<256, 256, 0, stream>>>(part, ao16);
  gemm_bt<1><<<dim3(2, 8), 256, 0, stream>>>(ao16, WoT, out, BS * QLEN, DMODEL, DMODEL);
}

// Round 16
// 287.820 us; speedup vs baseline: 1.2154x; 1.2154x over previous
//
#include <hip/hip_runtime.h>
#include <stdint.h>

// ---- problem constants (fixed by reference) ----
constexpr int DMODEL = 1024;
constexpr int NH     = 16;
constexpr int DHD    = 64;
constexpr int BS     = 8;
constexpr int QLEN   = 32;
constexpr int KLEN   = 4000;
constexpr int NCTX   = 20;
constexpr int PLEN   = 200;

typedef __bf16 bf16_t;
typedef bf16_t bf16x8 __attribute__((ext_vector_type(8)));
typedef float  f32x4  __attribute__((ext_vector_type(4)));

__device__ __forceinline__ uint16_t f2bf(float f) {
  uint32_t u = __float_as_uint(f);
  u += 0x7FFF + ((u >> 16) & 1);   // round-to-nearest-even
  return (uint16_t)(u >> 16);
}

#define GLOAD_LDS16(gsrc, ldst) \
  __builtin_amdgcn_global_load_lds((const __attribute__((address_space(1))) void*)(gsrc), \
                                   (__attribute__((address_space(3))) void*)(ldst), 16, 0, 0)

// ---------------- cast kv + input f32 -> bf16 (+ mask dtype flag, merged) ----------------
__global__ void cast_inputs(const float* __restrict__ kv, const float* __restrict__ inp,
                            uint16_t* __restrict__ kv16, uint16_t* __restrict__ in16,
                            const uint32_t* __restrict__ maskw, int* __restrict__ flag) {
  if (blockIdx.x == 0 && threadIdx.x == 0)
    *flag = (maskw[0] == 0x01010101u) ? 1 : 0;   // 1 = byte-bool, 0 = int32
  const int NKV4 = (BS * KLEN * DMODEL) / 4;
  const int NIN4 = (BS * QLEN * DMODEL) / 4;
  const int total = NKV4 + NIN4;
  for (int i = blockIdx.x * blockDim.x + threadIdx.x; i < total; i += gridDim.x * blockDim.x) {
    float4 v; uint16_t* dst; int di;
    if (i < NKV4) { v = ((const float4*)kv)[i]; dst = kv16; di = i; }
    else          { v = ((const float4*)inp)[i - NKV4]; dst = in16; di = i - NKV4; }
    ushort4 o; o.x = f2bf(v.x); o.y = f2bf(v.y); o.z = f2bf(v.z); o.w = f2bf(v.w);
    ((ushort4*)dst)[di] = o;
  }
}

// ---------------- weight transpose-cast: W[1024][1024] f32 -> WT[N][K] bf16 ----------------
__global__ void wtrans(const float* __restrict__ w0, const float* __restrict__ w1,
                       const float* __restrict__ w2, const float* __restrict__ w3,
                       uint16_t* __restrict__ out) {
  __shared__ uint16_t sm[64][65];
  const float* W = (blockIdx.z == 0) ? w0 : (blockIdx.z == 1) ? w1 : (blockIdx.z == 2) ? w2 : w3;
  uint16_t* o = out + (size_t)blockIdx.z * DMODEL * DMODEL;
  int k0 = blockIdx.y * 64, n0 = blockIdx.x * 64;
  int t = threadIdx.x;
  for (int i = 0; i < 16; ++i) {
    int s = t + i * 256; int r = s >> 6, c = s & 63;
    sm[r][c] = f2bf(W[(size_t)(k0 + r) * DMODEL + n0 + c]);
  }
  __syncthreads();
  for (int i = 0; i < 16; ++i) {
    int s = t + i * 256; int r = s >> 6, c = s & 63;
    o[(size_t)(n0 + r) * DMODEL + k0 + c] = sm[c][r];   // WT[n][k] = W[k][n]
  }
}

// ---------------- small bf16 GEMM (Q proj / out proj), BM=128 BN=64 (2x blocks) ----------
// 4 waves in 2x2; wave tile 64x32 (acc[4][2]). Staging: 12 chunks of 16 rows, 3/wave.
template <int OUT_F32>
__global__ void __launch_bounds__(256) gemm_bt(const uint16_t* __restrict__ A,
                                               const uint16_t* __restrict__ Bt,
                                               void* __restrict__ Cv,
                                               int M, int N, int K) {
  __shared__ __align__(16) uint16_t As[128 * 32];
  __shared__ __align__(16) uint16_t Bs[64 * 32];
  const int m0 = blockIdx.x * 128, n0 = blockIdx.y * 64;
  const int tid = threadIdx.x, lane = tid & 63, wave = tid >> 6;
  const int wm = wave >> 1, wn = wave & 1;
  const int l15 = lane & 15, g = lane >> 4;
  const int sr = lane >> 2, sc = (lane & 3) * 8;
  const int c0 = wave * 3, c1 = c0 + 1, c2 = c0 + 2;   // 3 chunks/wave, 12 total
  f32x4 acc[4][2] = {};
  const int KT = K / 32;
  for (int kt = 0; kt < KT; ++kt) {
    __syncthreads();
#pragma unroll
    for (int cq = 0; cq < 3; ++cq) {
      const int c = wave * 3 + cq;
      if (c < 8)   // A chunk: rows c*16..+15
        GLOAD_LDS16(A  + (size_t)(m0 + c * 16 + sr) * K + kt * 32 + sc, As + c * 512);
      else         // B chunk: rows (c-8)*16..+15
        GLOAD_LDS16(Bt + (size_t)(n0 + (c - 8) * 16 + sr) * K + kt * 32 + sc, Bs + (c - 8) * 512);
    }
    __syncthreads();
    bf16x8 a[4], b[2];
#pragma unroll
    for (int i = 0; i < 4; ++i)
      a[i] = *(const bf16x8*)&As[(wm * 64 + i * 16 + l15) * 32 + g * 8];
#pragma unroll
    for (int j = 0; j < 2; ++j)
      b[j] = *(const bf16x8*)&Bs[(wn * 32 + j * 16 + l15) * 32 + g * 8];
#pragma unroll
    for (int i = 0; i < 4; ++i)
#pragma unroll
      for (int j = 0; j < 2; ++j)
        acc[i][j] = __builtin_amdgcn_mfma_f32_16x16x32_bf16(a[i], b[j], acc[i][j], 0, 0, 0);
  }
#pragma unroll
  for (int i = 0; i < 4; ++i)
#pragma unroll
    for (int j = 0; j < 2; ++j) {
      int row = m0 + wm * 64 + i * 16 + g * 4;
      int col = n0 + wn * 32 + j * 16 + l15;
      if (OUT_F32) {
        float* C = (float*)Cv;
#pragma unroll
        for (int r = 0; r < 4; ++r) C[(size_t)(row + r) * N + col] = acc[i][j][r];
      } else {
        uint16_t* C = (uint16_t*)Cv;
#pragma unroll
        for (int r = 0; r < 4; ++r) C[(size_t)(row + r) * N + col] = f2bf(acc[i][j][r]);
      }
    }
}

// ---------------- merged K+V projection GEMM (exact round-9 text: measured 162 us) ----
__global__ void __launch_bounds__(512) gemm_kv(const uint16_t* __restrict__ A,
                                               const uint16_t* __restrict__ Bt,
                                               uint16_t* __restrict__ kmat,
                                               uint16_t* __restrict__ vt) {
  __shared__ __align__(16) uint16_t smem[65536];   // 128 KB
  const int orig = blockIdx.x;                      // 1000 = 8 * 125
  const int swz  = (orig & 7) * 125 + (orig >> 3);  // XCD-chunked bijection
  const int mb = swz >> 3, nb = swz & 7;            // n-fastest
  const int m0 = mb * 256, n0 = nb * 256;
  const int tid = threadIdx.x, lane = tid & 63, wid = tid >> 6;
  const int wm = wid >> 2, wn = wid & 3;            // 2x4 wave grid; wave tile 128x64
  const int l15 = lane & 15, g = lane >> 4;
  const int l3 = lane >> 3, l7 = lane & 7;
  const int cg = (l7 ^ (l3 & 7)) * 8;               // pre-swizzled source granule

  f32x4 acc[8][4] = {};

#define ABASE(bf) (smem + (bf) * 32768)
#define BBASE(bf) (smem + (bf) * 32768 + 16384)

  auto STAGE = [&](int bf, int kt) {
    const int colg = kt * 64 + cg;
#pragma unroll
    for (int ia = 0; ia < 4; ++ia) {                // 4 A-loads/wave: 8 rows each
      const int r0 = wid * 32 + ia * 8;
      GLOAD_LDS16(A + (size_t)(m0 + r0 + l3) * 1024 + colg, ABASE(bf) + r0 * 64);
    }
#pragma unroll
    for (int ib = 0; ib < 4; ++ib) {                // 4 B-loads/wave
      const int r0 = wid * 32 + ib * 8;
      GLOAD_LDS16(Bt + (size_t)(n0 + r0 + l3) * 1024 + colg, BBASE(bf) + r0 * 64);
    }
  };

  STAGE(0, 0);
  for (int kt = 0; kt < 16; ++kt) {
    const int bf = kt & 1;
    if (kt < 15) {
      STAGE(bf ^ 1, kt + 1);                         // 8 new loads in flight
      asm volatile("s_waitcnt vmcnt(8)" ::: "memory");  // tile kt landed; kt+1 stays in flight
    } else {
      asm volatile("s_waitcnt vmcnt(0)" ::: "memory");
    }
    asm volatile("s_barrier" ::: "memory");
#pragma unroll
    for (int kk = 0; kk < 2; ++kk) {
      bf16x8 af[8], bb[4];
#pragma unroll
      for (int mi = 0; mi < 8; ++mi) {
        const int row = wm * 128 + mi * 16 + l15;
        const int gr = (kk * 4 + g) ^ (row & 7);    // swizzled read -> conflict-free
        af[mi] = *(const bf16x8*)&ABASE(bf)[row * 64 + gr * 8];
      }
#pragma unroll
      for (int ni = 0; ni < 4; ++ni) {
        const int row = wn * 64 + ni * 16 + l15;
        const int gr = (kk * 4 + g) ^ (row & 7);
        bb[ni] = *(const bf16x8*)&BBASE(bf)[row * 64 + gr * 8];
      }
#pragma unroll
      for (int mi = 0; mi < 8; ++mi)
#pragma unroll
        for (int ni = 0; ni < 4; ++ni)
          acc[mi][ni] = __builtin_amdgcn_mfma_f32_16x16x32_bf16(af[mi], bb[ni], acc[mi][ni], 0, 0, 0);
    }
    asm volatile("s_barrier" ::: "memory");          // buf[bf] free for re-stage next iter
  }
#undef ABASE
#undef BBASE

  if (n0 < 1024) {
    // ---- K half: row-major store to kmat [32000][1024]
#pragma unroll
    for (int mi = 0; mi < 8; ++mi)
#pragma unroll
      for (int ni = 0; ni < 4; ++ni) {
        const int row = m0 + wm * 128 + mi * 16 + g * 4;
        const int col = n0 + wn * 64 + ni * 16 + l15;
#pragma unroll
        for (int r = 0; r < 4; ++r)
          kmat[(size_t)(row + r) * 1024 + col] = f2bf(acc[mi][ni][r]);
      }
  } else {
    // ---- V half: 256x256 LDS transpose (reuse all 128 KB) then coalesced vt store
#pragma unroll
    for (int mi = 0; mi < 8; ++mi)
#pragma unroll
      for (int ni = 0; ni < 4; ++ni) {
        const int dd = wn * 64 + ni * 16 + l15;        // head-dim within tile
        const int kk_tok = wm * 128 + mi * 16 + g * 4; // token within tile
#pragma unroll
        for (int r = 0; r < 4; ++r)
          smem[dd * 256 + kk_tok + r] = f2bf(acc[mi][ni][r]);
      }
    __syncthreads();
    const int hbase = (n0 - 1024) >> 6;               // 4 heads per 256-col tile
#pragma unroll
    for (int it = 0; it < 16; ++it) {
      const int sp = it * 512 + tid;                  // 8192 spans of 8 elems
      const int dd = sp >> 5, kk0 = (sp & 31) * 8;
      const int grow = m0 + kk0;                      // 8-span never straddles b (4000%8==0)
      const int b = grow / 4000, krel = grow - b * 4000;
      const int h = hbase + (dd >> 6), d = dd & 63;
      ulonglong2 v = *(const ulonglong2*)&smem[dd * 256 + kk0];
      *(ulonglong2*)&vt[(((size_t)(b * NH + h) * DHD + d) * KLEN) + krel] = v;
    }
  }
}

// ---------------- fused flash attention + collected (exact round-9 text) ----------------
__global__ void __launch_bounds__(256) fused_attn(const uint16_t* __restrict__ Q,
                                                  const uint16_t* __restrict__ Km,
                                                  const uint16_t* __restrict__ Vt,
                                                  const float* __restrict__ mask_add,
                                                  const void* __restrict__ maskb,
                                                  const int* __restrict__ flag,
                                                  const float* __restrict__ bias,
                                                  float* __restrict__ part,
                                                  float* __restrict__ coll) {
  __shared__ __align__(16) uint16_t plds[4][32 * 32];   // per-wave P tile (no barriers)
  const int kc = blockIdx.x, h = blockIdx.y, b = blockIdx.z;
  const int lane = threadIdx.x & 63, wave = threadIdx.x >> 6;
  const int l15 = lane & 15, g = lane >> 4;
  const int ctx = kc * 4 + wave;
  const int kbase = ctx * PLEN;
  const int fm = *flag;

  bf16x8 aq[2][2];
#pragma unroll
  for (int i = 0; i < 2; ++i)
#pragma unroll
    for (int ks = 0; ks < 2; ++ks)
      aq[i][ks] = *(const bf16x8*)&Q[(size_t)(b * QLEN + i * 16 + l15) * DMODEL + h * DHD + ks * 32 + g * 8];

  f32x4 o[2][4] = {};
  float mr[2][4], lr[2][4], cs[2][4];
#pragma unroll
  for (int i = 0; i < 2; ++i)
#pragma unroll
    for (int r = 0; r < 4; ++r) { mr[i][r] = -3e38f; lr[i][r] = 0.f; cs[i][r] = 0.f; }
  float cnt = 0.f;

  for (int t = 0; t < 7; ++t) {
    const int k0 = kbase + t * 32;
    bf16x8 kb[2][2];
#pragma unroll
    for (int j = 0; j < 2; ++j) {
      int kr = k0 + j * 16 + l15; if (kr > KLEN - 1) kr = KLEN - 1;
#pragma unroll
      for (int ks = 0; ks < 2; ++ks)
        kb[j][ks] = *(const bf16x8*)&Km[(size_t)(b * KLEN + kr) * DMODEL + h * DHD + ks * 32 + g * 8];
    }
    f32x4 sa[2][2] = {};
#pragma unroll
    for (int ks = 0; ks < 2; ++ks)
#pragma unroll
      for (int i = 0; i < 2; ++i)
#pragma unroll
        for (int j = 0; j < 2; ++j)
          sa[i][j] = __builtin_amdgcn_mfma_f32_16x16x32_bf16(aq[i][ks], kb[j][ks], sa[i][j], 0, 0, 0);

    int colc[2]; bool vd[2], vm[2]; float ma[2];
#pragma unroll
    for (int j = 0; j < 2; ++j) {
      int col = k0 + j * 16 + l15;
      vd[j] = (col < kbase + PLEN);
      int cc = col; if (cc > KLEN - 1) cc = KLEN - 1;
      colc[j] = cc;
      ma[j] = mask_add[b * KLEN + cc];
      bool mk = fm ? (((const uint8_t*)maskb)[b * KLEN + cc] != 0)
                   : (((const int*)maskb)[b * KLEN + cc] != 0);
      vm[j] = vd[j] && mk;
    }

    float sv[2][2][4];
    float tmax[2][4];
#pragma unroll
    for (int i = 0; i < 2; ++i)
#pragma unroll
      for (int r = 0; r < 4; ++r) {
        tmax[i][r] = -3e38f;
        const int q = i * 16 + g * 4 + r;
        const size_t brow = (size_t)(h * QLEN + q) * KLEN;
#pragma unroll
        for (int j = 0; j < 2; ++j) {
          float raw = sa[i][j][r] + ma[j] + bias[brow + colc[j]];
          cs[i][r] += vm[j] ? raw : 0.f;
          float x = vd[j] ? raw : -3e38f;
          sv[i][j][r] = x;
          tmax[i][r] = fmaxf(tmax[i][r], x);
        }
      }
#pragma unroll
    for (int j = 0; j < 2; ++j) cnt += vm[j] ? 1.f : 0.f;

#pragma unroll
    for (int i = 0; i < 2; ++i)
#pragma unroll
      for (int r = 0; r < 4; ++r) {
        float v = tmax[i][r];
        v = fmaxf(v, __shfl_xor(v, 1)); v = fmaxf(v, __shfl_xor(v, 2));
        v = fmaxf(v, __shfl_xor(v, 4)); v = fmaxf(v, __shfl_xor(v, 8));
        tmax[i][r] = v;
      }
    float scale[2][4];
#pragma unroll
    for (int i = 0; i < 2; ++i)
#pragma unroll
      for (int r = 0; r < 4; ++r) {
        float mn = fmaxf(mr[i][r], tmax[i][r]);
        scale[i][r] = __expf(mr[i][r] - mn);
        mr[i][r] = mn;
        lr[i][r] *= scale[i][r];
      }
#pragma unroll
    for (int i = 0; i < 2; ++i)
#pragma unroll
      for (int j2 = 0; j2 < 4; ++j2)
#pragma unroll
        for (int r = 0; r < 4; ++r)
          o[i][j2][r] *= scale[i][r];
#pragma unroll
    for (int i = 0; i < 2; ++i)
#pragma unroll
      for (int r = 0; r < 4; ++r) {
        const int q = i * 16 + g * 4 + r;
#pragma unroll
        for (int j = 0; j < 2; ++j) {
          float p = __expf(sv[i][j][r] - mr[i][r]);
          lr[i][r] += p;
          plds[wave][q * 32 + j * 16 + l15] = f2bf(p);
        }
      }
    bf16x8 ap[2];
#pragma unroll
    for (int i = 0; i < 2; ++i)
      ap[i] = *(const bf16x8*)&plds[wave][(i * 16 + l15) * 32 + g * 8];
    bf16x8 vb[4];
    int vc = k0 + g * 8; if (vc > KLEN - 8) vc = KLEN - 8;
#pragma unroll
    for (int j2 = 0; j2 < 4; ++j2)
      vb[j2] = *(const bf16x8*)&Vt[((size_t)((b * NH + h) * DHD + j2 * 16 + l15)) * KLEN + vc];
#pragma unroll
    for (int i = 0; i < 2; ++i)
#pragma unroll
      for (int j2 = 0; j2 < 4; ++j2)
        o[i][j2] = __builtin_amdgcn_mfma_f32_16x16x32_bf16(ap[i], vb[j2], o[i][j2], 0, 0, 0);
  }

#pragma unroll
  for (int i = 0; i < 2; ++i)
#pragma unroll
    for (int r = 0; r < 4; ++r) {
      float v = lr[i][r];
      v += __shfl_xor(v, 1); v += __shfl_xor(v, 2); v += __shfl_xor(v, 4); v += __shfl_xor(v, 8);
      lr[i][r] = v;
      float c = cs[i][r];
      c += __shfl_xor(c, 1); c += __shfl_xor(c, 2); c += __shfl_xor(c, 4); c += __shfl_xor(c, 8);
      cs[i][r] = c;
    }
  { float c = cnt; c += __shfl_xor(c, 1); c += __shfl_xor(c, 2); c += __shfl_xor(c, 4); c += __shfl_xor(c, 8); cnt = c; }

  float* pr = part + ((size_t)((b * NH + h) * NCTX + ctx)) * 32 * 72;
#pragma unroll
  for (int i = 0; i < 2; ++i)
#pragma unroll
    for (int j2 = 0; j2 < 4; ++j2)
#pragma unroll
      for (int r = 0; r < 4; ++r)
        pr[(i * 16 + g * 4 + r) * 72 + 8 + j2 * 16 + l15] = o[i][j2][r];
  if (l15 == 0) {
#pragma unroll
    for (int i = 0; i < 2; ++i)
#pragma unroll
      for (int r = 0; r < 4; ++r) {
        int q = i * 16 + g * 4 + r;
        pr[q * 72 + 0] = mr[i][r];
        pr[q * 72 + 1] = lr[i][r];
        coll[(((size_t)(b * NH + h)) * QLEN + q) * NCTX + ctx] = cs[i][r] / cnt;
      }
  }
}

// ---------------- combine 20 chunk partials -> ao16 ----------------
__global__ void __launch_bounds__(256) combine_attn(const float* __restrict__ part,
                                                    uint16_t* __restrict__ ao16) {
  const int t = threadIdx.x;
  const int row = blockIdx.x * 16 + (t >> 4);   // (b*16+h)*32+q
  const int ln = t & 15;
  const int bh = row >> 5, q = row & 31;
  const float* p0 = part + ((size_t)bh * 640 + q) * 72;   // 640 = 20*32
  float M = -3e38f;
#pragma unroll
  for (int c = 0; c < NCTX; ++c) M = fmaxf(M, p0[(size_t)c * 2304]);  // 2304 = 32*72
  float Z = 0.f, o0 = 0.f, o1 = 0.f, o2 = 0.f, o3 = 0.f;
  const int d0 = ln * 4;
  for (int c = 0; c < NCTX; ++c) {
    const float* pc = p0 + (size_t)c * 2304;
    float e = __expf(pc[0] - M);
    Z += e * pc[1];
    float4 ov = *(const float4*)&pc[8 + d0];
    o0 += e * ov.x; o1 += e * ov.y; o2 += e * ov.z; o3 += e * ov.w;
  }
  float iz = 1.f / Z;
  const int b = bh >> 4, h = bh & 15;
  ushort4 w; w.x = f2bf(o0 * iz); w.y = f2bf(o1 * iz); w.z = f2bf(o2 * iz); w.w = f2bf(o3 * iz);
  *(ushort4*)&ao16[(size_t)(b * QLEN + q) * DMODEL + h * DHD + d0] = w;
}

extern "C" void kernel_launch(void* const* d_in, const int* in_sizes, int n_in,
                              void* d_out, int out_size, void* d_ws, size_t ws_size,
                              hipStream_t stream) {
  const float* input     = (const float*)d_in[0];
  const float* kv        = (const float*)d_in[1];
  const float* mask_add  = (const float*)d_in[2];
  const void*  mask_bool = d_in[3];
  const float* bias      = (const float*)d_in[4];
  const float* Wq        = (const float*)d_in[5];
  const float* Wk        = (const float*)d_in[6];
  const float* Wv        = (const float*)d_in[7];
  const float* Wo        = (const float*)d_in[8];
  float* out  = (float*)d_out;
  float* coll = out + (size_t)BS * QLEN * DMODEL;

  char* ws = (char*)d_ws;
  size_t off = 0;
  auto alloc = [&](size_t bytes) { char* p = ws + off; off += (bytes + 255) & ~(size_t)255; return p; };
  uint16_t* kv16 = (uint16_t*)alloc((size_t)BS * KLEN * DMODEL * 2);
  uint16_t* in16 = (uint16_t*)alloc((size_t)BS * QLEN * DMODEL * 2);
  uint16_t* wt   = (uint16_t*)alloc((size_t)4 * DMODEL * DMODEL * 2);
  uint16_t* q16  = (uint16_t*)alloc((size_t)BS * QLEN * DMODEL * 2);
  uint16_t* kmat = (uint16_t*)alloc((size_t)BS * KLEN * DMODEL * 2);
  uint16_t* vt   = (uint16_t*)alloc((size_t)BS * KLEN * DMODEL * 2);
  float*    part = (float*)   alloc((size_t)BS * NH * NCTX * 32 * 72 * 4);
  uint16_t* ao16 = (uint16_t*)alloc((size_t)BS * QLEN * DMODEL * 2);
  int*      flag = (int*)alloc(256);

  uint16_t* WqT  = wt;
  uint16_t* WkvT = wt + (size_t)DMODEL * DMODEL;      // [WkT; WvT] contiguous, 2048 rows
  uint16_t* WoT  = wt + (size_t)3 * DMODEL * DMODEL;

  cast_inputs<<<2048, 256, 0, stream>>>(kv, input, kv16, in16,
                                        (const uint32_t*)mask_bool, flag);
  wtrans<<<dim3(16, 16, 4), 256, 0, stream>>>(Wq, Wk, Wv, Wo, wt);
  gemm_bt<0><<<dim3(2, 16), 256, 0, stream>>>(in16, WqT, q16, BS * QLEN, DMODEL, DMODEL);
  gemm_kv<<<1000, 512, 0, stream>>>(kv16, WkvT, kmat, vt);
  fused_attn<<<dim3(5, NH, BS), 256, 0, stream>>>(q16, kmat, vt, mask_add, mask_bool, flag,
                                                  bias, part, coll);
  combine_attn<<<256, 256, 0, stream>>>(part, ao16);
  gemm_bt<1><<<dim3(2, 16), 256, 0, stream>>>(ao16, WoT, out, BS * QLEN, DMODEL, DMODEL);
}